// Round 13
// baseline (2901.594 us; speedup 1.0000x reference)
//
#include <hip/hip_runtime.h>

typedef unsigned int u32;

#define NIN 7
#define NB 256
#define NS 2048

__device__ __forceinline__ float fastrcp(float x){ return __builtin_amdgcn_rcpf(x); }
__device__ __forceinline__ float sigf(float x){ return fastrcp(1.f + __expf(-x)); }
__device__ __forceinline__ float tanhf_(float x){ return 1.f - 2.f*fastrcp(1.f + __expf(2.f*x)); }

// soft barrier: drain LDS only (lgkmcnt), leave global loads/stores in flight.
// All in-loop cross-wave traffic is LDS; out[] is write-only, x is read-only.
__device__ __forceinline__ void softbar(){
  asm volatile("s_waitcnt lgkmcnt(0)" ::: "memory");
  __builtin_amdgcn_s_barrier();
}

// RNE f16 pack (v_cvt_f16_f32 is RNE; activations stay f32 everywhere)
__device__ __forceinline__ u32 pkh(float a, float b){
  unsigned short ua = __builtin_bit_cast(unsigned short, (_Float16)a);
  unsigned short ub = __builtin_bit_cast(unsigned short, (_Float16)b);
  return (u32)ua | ((u32)ub << 16);
}

template<int J>
__device__ __forceinline__ float rlf(float v){
  return __uint_as_float((unsigned)__builtin_amdgcn_readlane((int)__float_as_uint(v), J));
}
__device__ __forceinline__ float rlfv(float v, int j){   // j compile-time after unroll
  return __uint_as_float((unsigned)__builtin_amdgcn_readlane((int)__float_as_uint(v), j));
}

// acc += f16(lo/hi of wp) * act(f32) + acc, f32 accumulate.
__device__ __forceinline__ float mxl(float acc, u32 wp, float a){
  asm("v_fma_mix_f32 %0, %1, %2, %3 op_sel_hi:[1,0,0]"
      : "=v"(acc) : "v"(wp), "s"(a), "0"(acc));
  return acc;
}
__device__ __forceinline__ float mxh(float acc, u32 wp, float a){
  asm("v_fma_mix_f32 %0, %1, %2, %3 op_sel:[1,0,0] op_sel_hi:[1,0,0]"
      : "=v"(acc) : "v"(wp), "s"(a), "0"(acc));
  return acc;
}
__device__ __forceinline__ float mxlv(float acc, u32 wp, float a){
  asm("v_fma_mix_f32 %0, %1, %2, %3 op_sel_hi:[1,0,0]"
      : "=v"(acc) : "v"(wp), "v"(a), "0"(acc));
  return acc;
}
__device__ __forceinline__ float mxhv(float acc, u32 wp, float a){
  asm("v_fma_mix_f32 %0, %1, %2, %3 op_sel:[1,0,0] op_sel_hi:[1,0,0]"
      : "=v"(acc) : "v"(wp), "v"(a), "0"(acc));
  return acc;
}

// identical gate math -> bit-identical h wherever computed
__device__ __forceinline__ float gate4(float zi, float zf, float zg, float zo, float& c){
  c = sigf(zf)*c + sigf(zi)*tanhf_(zg);
  return sigf(zo)*tanhf_(c);
}

// 8-elem x+bias dot: w[KB..KB+3] (8 f16) . {v0,v1}
#define XD(a0, a1, KB, v0, v1) { \
  a0 = mxlv(a0, w[(KB)+0], (v0).x); a1 = mxhv(a1, w[(KB)+0], (v0).y); \
  a0 = mxlv(a0, w[(KB)+1], (v0).z); a1 = mxhv(a1, w[(KB)+1], (v0).w); \
  a0 = mxlv(a0, w[(KB)+2], (v1).x); a1 = mxhv(a1, w[(KB)+2], (v1).y); \
  a0 = mxlv(a0, w[(KB)+3], (v1).z); a1 = mxhv(a1, w[(KB)+3], (v1).w); }

// ---- LDS-broadcast dots (uniform float4 reads ride the LDS pipe) ----
#define LMX2(a0, a1, s0, s1, KA, KS, H4) { _Pragma("unroll") \
  for (int c_ = 0; c_ < 16; c_++){ \
    float4 h_ = (H4)[c_]; \
    a0 = mxlv(a0, w[(KA)+2*c_],   h_.x); a1 = mxhv(a1, w[(KA)+2*c_],   h_.y); \
    a0 = mxlv(a0, w[(KA)+2*c_+1], h_.z); a1 = mxhv(a1, w[(KA)+2*c_+1], h_.w); \
    s0 = mxlv(s0, w[(KS)+2*c_],   h_.x); s1 = mxhv(s1, w[(KS)+2*c_],   h_.y); \
    s0 = mxlv(s0, w[(KS)+2*c_+1], h_.z); s1 = mxhv(s1, w[(KS)+2*c_+1], h_.w); } }

#define LMX1(a0, a1, KA, H4) { _Pragma("unroll") \
  for (int c_ = 0; c_ < 16; c_++){ \
    float4 h_ = (H4)[c_]; \
    a0 = mxlv(a0, w[(KA)+2*c_],   h_.x); a1 = mxhv(a1, w[(KA)+2*c_],   h_.y); \
    a0 = mxlv(a0, w[(KA)+2*c_+1], h_.z); a1 = mxhv(a1, w[(KA)+2*c_+1], h_.w); } }

#define LMXH(z0, z1, KB, H4) { _Pragma("unroll") \
  for (int c_ = 0; c_ < 8; c_++){ \
    float4 h_ = (H4)[c_]; \
    z0 = mxlv(z0, w[(KB)+2*c_],   h_.x); z1 = mxhv(z1, w[(KB)+2*c_],   h_.y); \
    z0 = mxlv(z0, w[(KB)+2*c_+1], h_.z); z1 = mxhv(z1, w[(KB)+2*c_+1], h_.w); } }

// ---- readlane dots (prologue only) ----
#define MX2(a0, a1, s0, s1, KA, KS, SRC) { _Pragma("unroll") \
  for (int k_ = 0; k_ < 32; k_++){ \
    float e0_ = rlfv(SRC, 2*k_), e1_ = rlfv(SRC, 2*k_+1); \
    a0 = mxl(a0, w[(KA)+k_], e0_); a1 = mxh(a1, w[(KA)+k_], e1_); \
    s0 = mxl(s0, w[(KS)+k_], e0_); s1 = mxh(s1, w[(KS)+k_], e1_); } }

#define MX1(a0, a1, KA, SRC) { _Pragma("unroll") \
  for (int k_ = 0; k_ < 32; k_++){ \
    float e0_ = rlfv(SRC, 2*k_), e1_ = rlfv(SRC, 2*k_+1); \
    a0 = mxl(a0, w[(KA)+k_], e0_); a1 = mxh(a1, w[(KA)+k_], e1_); } }

// MLP with 4 accumulator chains per layer (shorter serial dep for the TAIL)
#define MLPX(HS_, M1B, B1V, M2B, B2V, dres) { \
  float q0_ = (B1V), q1_ = 0.f, q2_ = 0.f, q3_ = 0.f; \
  _Pragma("unroll") \
  for (int j_ = 0; j_ < 16; j_++){ \
    float e0_ = rlfv(HS_, 2*j_), e1_ = rlfv(HS_, 2*j_+1); \
    if ((j_&1)==0){ q0_ = mxl(q0_, w[(M1B)+j_], e0_); q1_ = mxh(q1_, w[(M1B)+j_], e1_); } \
    else          { q2_ = mxl(q2_, w[(M1B)+j_], e0_); q3_ = mxh(q3_, w[(M1B)+j_], e1_); } } \
  float qq_ = fmaxf((q0_+q2_) + (q1_+q3_), 0.f); \
  float f0_ = (B2V), f1_ = 0.f, f2_ = 0.f, f3_ = 0.f; \
  _Pragma("unroll") \
  for (int j_ = 0; j_ < 8; j_++){ \
    float e0_ = rlfv(qq_, 2*j_), e1_ = rlfv(qq_, 2*j_+1); \
    if ((j_&1)==0){ f0_ = mxl(f0_, w[(M2B)+j_], e0_); f1_ = mxh(f1_, w[(M2B)+j_], e1_); } \
    else          { f2_ = mxl(f2_, w[(M2B)+j_], e0_); f3_ = mxh(f3_, w[(M2B)+j_], e1_); } } \
  dres = (f0_+f2_) + (f1_+f3_); }

__global__ __launch_bounds__(512, 2) void mtinn_kernel(
    const float* __restrict__ x,
    const float* wihs, const float* whhs, const float* bihs, const float* bhhs,
    const float* wiha, const float* whha, const float* biha, const float* bhha,
    const float* wihv, const float* whhv, const float* bihv, const float* bhhv,
    const float* wihp, const float* whhp, const float* bihp, const float* bhhp,
    const float* wa1, const float* ba1, const float* wa2, const float* ba2,
    const float* wv1, const float* bv1, const float* wv2, const float* bv2,
    const float* wp1, const float* bp1, const float* wp2, const float* bp2,
    float* __restrict__ out)
{
  __shared__ __align__(16) float ZS[2][256];   // shared-cell z, double buffered
  __shared__ __align__(16) float ZC[3][128];   // cell z (single buffer: TOP->TAIL)
  __shared__ __align__(16) float HS[64];       // hs(t+1), computed once by w4
  __shared__ __align__(16) float HA[32], HV[32];
  __shared__ __align__(16) float HPb[2][32];   // h_p double-buffered (deferred MLP reads old)
  __shared__ __align__(16) float XL[4][8];     // x ring; slot[7] = 1.0 (bias trick)

  const int tid  = threadIdx.x;
  const int wave = tid >> 6, lane = tid & 63, l = lane & 31;
  const int b    = blockIdx.x;
  const float* xb = x + (size_t)b * NS * NIN;

  // roles (SIMD = wave&3):
  //   wave | phase A                        | phase B
  //   w0   | x-prefetch issue               | TAIL (3 gates + att,vel MLPs)
  //   w4   | deferred POS MLP (t-1) + T_hs  | idle
  //   w1   | TOP att rows 64-127            | WIN att1 + sh_i
  //   w5   | TOP vel rows 0-63              | WIN vel0
  //   w2   | TOP vel rows 64-127            | WIN vel1 + sh_f
  //   w6   | TOP pos rows 0-63              | WIN pos0 + sh_g
  //   w3   | TOP pos rows 64-127            | WIN pos1
  //   w7   | TOP att rows 0-63              | WIN att0 + sh_o
  const bool isWin = (wave != 0 && wave != 4);
  const int  wc    = (wave==1||wave==7) ? 0 : (wave==2||wave==5) ? 1 : 2;
  const int  wrb   = (wave <= 3) ? 64 : 0;
  const bool isSh  = (wave==1 || wave==2 || wave==6 || wave==7);
  const int  qoff  = (wave==1) ? 0 : (wave==2) ? 64 : (wave==6) ? 128 : 192;
  const int  mi = lane & 15, mm = lane % 3;

  // ---- packed f16 register weights, per-wave union ----
  u32 w[88];
#pragma unroll
  for (int i = 0; i < 88; i++) w[i] = 0u;
  float b1a=0.f,b2a=0.f,b1v=0.f,b2v=0.f,b1p=0.f,b2p=0.f;

  if (isWin){
    const float* wih = (wc==0) ? wiha : (wc==1) ? wihv : wihp;
    const float* whh = (wc==0) ? whha : (wc==1) ? whhv : whhp;
    const float* bi  = (wc==0) ? biha : (wc==1) ? bihv : bihp;
    const float* bh  = (wc==0) ? bhha : (wc==1) ? bhhv : bhhp;
    const int L = (wc==0) ? 71 : (wc==1) ? 74 : 67;
    const int r = wrb + lane;
#pragma unroll
    for (int k=0;k<16;k++) w[k] = pkh(whh[r*32+2*k], whh[r*32+2*k+1]);
#pragma unroll
    for (int k=0;k<32;k++) w[16+k] = pkh(wih[r*L+2*k], wih[r*L+2*k+1]);
    const float bsum = bi[r] + bh[r];
    if (wc==0){
      w[48]=pkh(wih[r*L+64],wih[r*L+65]); w[49]=pkh(wih[r*L+66],wih[r*L+67]);
      w[50]=pkh(wih[r*L+68],wih[r*L+69]); w[51]=pkh(wih[r*L+70], bsum);
    } else if (wc==1){
      w[48]=pkh(wih[r*L+67],wih[r*L+68]); w[49]=pkh(wih[r*L+69],wih[r*L+70]);
      w[50]=pkh(wih[r*L+71],wih[r*L+72]); w[51]=pkh(wih[r*L+73], bsum);
    } else {
      w[51]=pkh(0.f, bsum);                     // pos: no x-weights
    }
  }
  if (isSh){
    const int r = qoff + lane;
#pragma unroll
    for (int k=0;k<32;k++) w[52+k] = pkh(whhs[r*64+2*k], whhs[r*64+2*k+1]);
    w[84]=pkh(wihs[r*7+0],wihs[r*7+1]); w[85]=pkh(wihs[r*7+2],wihs[r*7+3]);
    w[86]=pkh(wihs[r*7+4],wihs[r*7+5]); w[87]=pkh(wihs[r*7+6], bihs[r]+bhhs[r]);
  }
  if (wave == 0){
#pragma unroll
    for (int k=0;k<16;k++){
      w[k]    = pkh(wa1[mi*32+2*k], wa1[mi*32+2*k+1]);
      w[16+k] = pkh(wv1[mi*32+2*k], wv1[mi*32+2*k+1]);
    }
#pragma unroll
    for (int k=0;k<8;k++){
      w[48+k] = pkh(wa2[mm*16+2*k], wa2[mm*16+2*k+1]);
      w[56+k] = pkh(wv2[mm*16+2*k], wv2[mm*16+2*k+1]);
    }
#pragma unroll
    for (int g=0; g<4; g++){
      int rr = g*32 + l;
      w[72+2*g]   = pkh(wihv[rr*74+64], wihv[rr*74+65]);
      w[72+2*g+1] = pkh(wihv[rr*74+66], 0.f);
      w[80+2*g]   = pkh(wihp[rr*67+64], wihp[rr*67+65]);
      w[80+2*g+1] = pkh(wihp[rr*67+66], 0.f);
    }
    b1a=ba1[mi]; b2a=ba2[mm]; b1v=bv1[mi]; b2v=bv2[mm];
  }
  if (wave == 4){
#pragma unroll
    for (int k=0;k<16;k++) w[k] = pkh(wp1[mi*32+2*k], wp1[mi*32+2*k+1]);
#pragma unroll
    for (int k=0;k<8;k++)  w[16+k] = pkh(wp2[mm*16+2*k], wp2[mm*16+2*k+1]);
    b1p=bp1[mi]; b2p=bp2[mm];
  }

  // ---- LDS init ----
  if (tid < 32) HA[tid]=0.f;
  else if (tid < 64)  HV[tid-32]=0.f;
  else if (tid < 96)  HPb[0][tid-64]=0.f;
  else if (tid < 128) HPb[1][tid-96]=0.f;
  if (tid < 8){
    XL[0][tid] = (tid<7) ? xb[tid]         : 1.f;
    XL[1][tid] = (tid<7) ? xb[NIN+tid]     : 1.f;
    XL[2][tid] = (tid<7) ? xb[2*NIN+tid]   : 1.f;
    XL[3][tid] = 1.f;
  }
  __syncthreads();

  // ---- prologue: zS(0) ----
  if (isSh){
    const float4* X0 = (const float4*)XL[0];
    float4 xa = X0[0], xb4 = X0[1];
    float s0=0.f, s1=0.f; XD(s0,s1,84,xa,xb4);
    ZS[0][qoff + lane] = s0 + s1;
  }
  __syncthreads();

  float c_s = 0.f;                          // live in w4 (T_hs)
  float c_a = 0.f, c_v = 0.f, c_p = 0.f;    // wave 0
  float zpart = 0.f;

  // ---- prologue: hs(0), zpart(0), zS(1); w4 warms its c_s ----
  if (isWin){
    float zi_=ZS[0][lane], zf_=ZS[0][64+lane], zg_=ZS[0][128+lane], zo_=ZS[0][192+lane];
    float hsv = gate4(zi_,zf_,zg_,zo_, c_s);
    const float4* X0 = (const float4*)XL[0];
    float4 xa = X0[0], xb4 = X0[1];
    float a0=0.f, a1=0.f; XD(a0,a1,48,xa,xb4);
    if (isSh){
      const float4* X1 = (const float4*)XL[1];
      float4 xc = X1[0], xd = X1[1];
      float s0=0.f, s1=0.f; XD(s0,s1,84,xc,xd);
      MX2(a0,a1,s0,s1,16,52,hsv);
      ZS[1][qoff + lane] = s0 + s1;
    } else {
      MX1(a0,a1,16,hsv);
    }
    zpart = a0 + a1;
  } else if (wave == 4){
    float zi_=ZS[0][lane], zf_=ZS[0][64+lane], zg_=ZS[0][128+lane], zo_=ZS[0][192+lane];
    gate4(zi_,zf_,zg_,zo_, c_s);              // establish c_s(0); h discarded
  }
  __syncthreads();

  // ================= pipelined recurrence =================
#pragma unroll 1
  for (int t = 0; t < NS; t++){
    float xpre = 0.f;
    // ---- PHASE A ----
    if (wave == 0){
      if (lane < 7){
        const int tf = (t+3 < NS) ? t+3 : NS-1;
        xpre = xb[(size_t)tf*NIN + lane];        // stays in flight across softbar
      }
    } else if (wave == 4){
      // T_hs: hs(t+1) from zS(t+1), computed once
      const float* Zsrc = ZS[(t+1)&1];
      float zi_=Zsrc[lane], zf_=Zsrc[64+lane], zg_=Zsrc[128+lane], zo_=Zsrc[192+lane];
      float hsv2 = gate4(zi_,zf_,zg_,zo_, c_s);
      HS[lane] = hsv2;
      if (t > 0){                                     // deferred POS MLP for step t-1
        float hp_ = HPb[(t^1)&1][l];
        float dP; MLPX(hp_, 0, b1p, 16, b2p, dP);
        if (lane < 3) out[((size_t)b*NS + (t-1))*9 + 6 + lane] = dP;
      }
    } else {
      // TOP: z(t) = zpart(t) + Whh . h(t-1)   (h via uniform LDS float4 reads)
      const float4* H4 = (const float4*)((wc==0) ? HA : (wc==1) ? HV : HPb[(t^1)&1]);
      float z0 = zpart, z1 = 0.f;
      LMXH(z0,z1,0,H4);
      ZC[wc][wrb + lane] = z0 + z1;
    }
    softbar();   // #1 : ZC(t), HS(t+1) visible (LDS only; globals stay in flight)

    // ---- PHASE B ----
    if (wave == 0){
      // ================= TAIL =================
      __builtin_amdgcn_s_setprio(1);
      float zai=ZC[0][l], zaf=ZC[0][32+l], zag=ZC[0][64+l], zao=ZC[0][96+l];
      float zvi=ZC[1][l], zvf=ZC[1][32+l], zvg=ZC[1][64+l], zvo=ZC[1][96+l];
      float zpi=ZC[2][l], zpf=ZC[2][32+l], zpg=ZC[2][64+l], zpo=ZC[2][96+l];
      float* ob = out + ((size_t)b*NS + t)*9;
      // ATT
      float ha = gate4(zai,zaf,zag,zao, c_a);
      if (lane < 32) HA[lane] = ha;
      float dA; MLPX(ha, 0, b1a, 48, b2a, dA);
      if (lane < 3) ob[lane] = dA;
      float dx=rlf<0>(dA), dy=rlf<1>(dA), dz=rlf<2>(dA);
      // VEL (+ d_att columns)
      zvi = mxl(zvi, w[72], dx); zvi = mxh(zvi, w[72], dy); zvi = mxl(zvi, w[73], dz);
      zvf = mxl(zvf, w[74], dx); zvf = mxh(zvf, w[74], dy); zvf = mxl(zvf, w[75], dz);
      zvg = mxl(zvg, w[76], dx); zvg = mxh(zvg, w[76], dy); zvg = mxl(zvg, w[77], dz);
      zvo = mxl(zvo, w[78], dx); zvo = mxh(zvo, w[78], dy); zvo = mxl(zvo, w[79], dz);
      float hv = gate4(zvi,zvf,zvg,zvo, c_v);
      if (lane < 32) HV[lane] = hv;
      float dV; MLPX(hv, 16, b1v, 56, b2v, dV);
      if (lane < 3) ob[3+lane] = dV;
      dx=rlf<0>(dV); dy=rlf<1>(dV); dz=rlf<2>(dV);
      // POS (+ d_vel columns); MLP deferred to w4 next phase A
      zpi = mxl(zpi, w[80], dx); zpi = mxh(zpi, w[80], dy); zpi = mxl(zpi, w[81], dz);
      zpf = mxl(zpf, w[82], dx); zpf = mxh(zpf, w[82], dy); zpf = mxl(zpf, w[83], dz);
      zpg = mxl(zpg, w[84], dx); zpg = mxh(zpg, w[84], dy); zpg = mxl(zpg, w[85], dz);
      zpo = mxl(zpo, w[86], dx); zpo = mxh(zpo, w[86], dy); zpo = mxl(zpo, w[87], dz);
      float hp_ = gate4(zpi,zpf,zpg,zpo, c_p);
      if (lane < 32) HPb[t&1][lane] = hp_;
      __builtin_amdgcn_s_setprio(0);
      if (lane < 7) XL[(t+3)&3][lane] = xpre;          // vmcnt wait lands here, hidden by TAIL
    } else if (isWin){
      // ============ WIN: zpart(t+1), zS(t+2) (hs via uniform LDS reads) ============
      const float4* H4 = (const float4*)HS;
      const float4* X1 = (const float4*)XL[(t+1)&3];
      float4 xa = X1[0], xb4 = X1[1];
      float a0=0.f, a1=0.f; XD(a0,a1,48,xa,xb4);
      if (isSh){
        const float4* X2 = (const float4*)XL[(t+2)&3];
        float4 xc = X2[0], xd = X2[1];
        float s0=0.f, s1=0.f; XD(s0,s1,84,xc,xd);
        LMX2(a0,a1,s0,s1,16,52,H4);
        ZS[t&1][qoff + lane] = s0 + s1;
      } else {
        LMX1(a0,a1,16,H4);
      }
      zpart = a0 + a1;
    }
    softbar();   // #2
  }

  // ---- epilogue: POS MLP for t = NS-1 ----
  __syncthreads();
  if (wave == 4){
    float hp_ = HPb[(NS-1)&1][l];
    float dP; MLPX(hp_, 0, b1p, 16, b2p, dP);
    if (lane < 3) out[((size_t)b*NS + (NS-1))*9 + 6 + lane] = dP;
  }
}

extern "C" void kernel_launch(void* const* d_in, const int* in_sizes, int n_in,
                              void* d_out, int out_size, void* d_ws, size_t ws_size,
                              hipStream_t stream) {
  (void)in_sizes; (void)n_in; (void)d_ws; (void)ws_size; (void)out_size;
  const float* X    = (const float*)d_in[0];
  const float* Wihs = (const float*)d_in[1];
  const float* Whhs = (const float*)d_in[2];
  const float* Bihs = (const float*)d_in[3];
  const float* Bhhs = (const float*)d_in[4];
  const float* Wiha = (const float*)d_in[5];
  const float* Whha = (const float*)d_in[6];
  const float* Biha = (const float*)d_in[7];
  const float* Bhha = (const float*)d_in[8];
  const float* Wihv = (const float*)d_in[9];
  const float* Whhv = (const float*)d_in[10];
  const float* Bihv = (const float*)d_in[11];
  const float* Bhhv = (const float*)d_in[12];
  const float* Wihp = (const float*)d_in[13];
  const float* Whhp = (const float*)d_in[14];
  const float* Bihp = (const float*)d_in[15];
  const float* Bhhp = (const float*)d_in[16];
  const float* Wa1  = (const float*)d_in[17];
  const float* Ba1  = (const float*)d_in[18];
  const float* Wa2  = (const float*)d_in[19];
  const float* Ba2  = (const float*)d_in[20];
  const float* Wv1  = (const float*)d_in[21];
  const float* Bv1  = (const float*)d_in[22];
  const float* Wv2  = (const float*)d_in[23];
  const float* Bv2  = (const float*)d_in[24];
  const float* Wp1  = (const float*)d_in[25];
  const float* Bp1  = (const float*)d_in[26];
  const float* Wp2  = (const float*)d_in[27];
  const float* Bp2  = (const float*)d_in[28];
  float* OUTP = (float*)d_out;

  mtinn_kernel<<<dim3(NB), dim3(512), 0, stream>>>(
      X, Wihs, Whhs, Bihs, Bhhs,
      Wiha, Whha, Biha, Bhha,
      Wihv, Whhv, Bihv, Bhhv,
      Wihp, Whhp, Bihp, Bhhp,
      Wa1, Ba1, Wa2, Ba2, Wv1, Bv1, Wv2, Bv2, Wp1, Bp1, Wp2, Bp2,
      OUTP);
}